// Round 2
// baseline (253.269 us; speedup 1.0000x reference)
//
#include <hip/hip_runtime.h>
#include <math.h>

// MoE top-2 router, fused. Round 2: barrier-free K-loop, wave-private MFMA
// fragments straight from global (fp32 -> split-bf16 in regs), W pre-converted
// to bf16 hi/lo in d_ws, 4-way K-split for 16 waves/CU.
//
// x: [16384, 2048] fp32, W: [64, 2048] fp32.
// outputs (concat, fp32): mask [T,64], idx-as-float [T,2], router_probs [T,64], probs [T,64]

#define D_DIM 2048
#define E_DIM 64
#define TPB 16             // tokens per block (one 16-row MFMA tile)
#define KSPLIT 4           // waves per block, each covers D_DIM/KSPLIT = 512
#define KSTEPS 16          // 512 / 32 per wave

typedef __bf16 bf16x8 __attribute__((ext_vector_type(8)));
typedef unsigned short us8 __attribute__((ext_vector_type(8)));
typedef float f32x4 __attribute__((ext_vector_type(4)));

static __device__ __forceinline__ unsigned short f2bf(float f) {
    unsigned int u = __float_as_uint(f);
    u += 0x7fffu + ((u >> 16) & 1u);   // RNE
    return (unsigned short)(u >> 16);
}
static __device__ __forceinline__ float bf2f(unsigned short h) {
    return __uint_as_float(((unsigned int)h) << 16);
}
static __device__ __forceinline__ void split4(const float4 v, ushort4* h, ushort4* l) {
    h->x = f2bf(v.x); l->x = f2bf(v.x - bf2f(h->x));
    h->y = f2bf(v.y); l->y = f2bf(v.y - bf2f(h->y));
    h->z = f2bf(v.z); l->z = f2bf(v.z - bf2f(h->z));
    h->w = f2bf(v.w); l->w = f2bf(v.w - bf2f(h->w));
}

// ---- pre-convert W (64x2048 fp32) -> bf16 hi/lo in workspace ----
__global__ __launch_bounds__(256, 1) void convert_w(
    const float4* __restrict__ W4, unsigned short* __restrict__ WH,
    unsigned short* __restrict__ WL)
{
    int i = blockIdx.x * 256 + threadIdx.x;   // float4 index, 32768 total
    float4 v = W4[i];
    ushort4 h, l;
    split4(v, &h, &l);
    *(ushort4*)&WH[i * 4] = h;
    *(ushort4*)&WL[i * 4] = l;
}

__global__ __launch_bounds__(256, 4) void router_fused(
    const float* __restrict__ x,
    const unsigned short* __restrict__ WH, const unsigned short* __restrict__ WL,
    float* __restrict__ mask_out, float* __restrict__ idx_out,
    float* __restrict__ rp_out, float* __restrict__ probs_out)
{
    __shared__ float PART[KSPLIT * 64 * 16];   // 16 KB: per-wave partial acc
    __shared__ float LG[TPB * 65];             // summed logits, padded

    const int tid  = threadIdx.x;
    const int lane = tid & 63;
    const int wv   = tid >> 6;       // K-split slice 0..3
    const int quad = lane >> 4;
    const int l16  = lane & 15;
    const int t0   = blockIdx.x * TPB;

    const float4* x4 = (const float4*)x;
    // A-fragment: row = t0 + l16, k = wv*512 + ks*32 + quad*8 (+j)
    const size_t xbase = (size_t)(t0 + l16) * 512 + wv * 128 + quad * 2; // float4 units
    // B-fragment: row = 16n + l16, same k window (short units)
    const int wbase = l16 * 2048 + wv * 512 + quad * 8;

    f32x4 acc[4];
    #pragma unroll
    for (int n = 0; n < 4; ++n) { f32x4 z = {0.f, 0.f, 0.f, 0.f}; acc[n] = z; }

    float4 xa = x4[xbase];
    float4 xb = x4[xbase + 1];

    for (int ks = 0; ks < KSTEPS; ++ks) {
        // split current 8 x-values into bf16 hi/lo fragments
        ushort4 h0, l0, h1, l1;
        split4(xa, &h0, &l0);
        split4(xb, &h1, &l1);
        union { us8 u; bf16x8 b; } ua, ul;
        ua.u = (us8){h0.x, h0.y, h0.z, h0.w, h1.x, h1.y, h1.z, h1.w};
        ul.u = (us8){l0.x, l0.y, l0.z, l0.w, l1.x, l1.y, l1.z, l1.w};
        bf16x8 ah = ua.b, al = ul.b;

        // prefetch next k-step's x (no barriers anywhere -> stays in flight)
        if (ks + 1 < KSTEPS) {
            xa = x4[xbase + (ks + 1) * 8];
            xb = x4[xbase + (ks + 1) * 8 + 1];
        }

        const int ko = ks * 32;
        #pragma unroll
        for (int n = 0; n < 4; ++n) {
            bf16x8 bh = *(const bf16x8*)(WH + wbase + n * 32768 + ko);
            bf16x8 bl = *(const bf16x8*)(WL + wbase + n * 32768 + ko);
            acc[n] = __builtin_amdgcn_mfma_f32_16x16x32_bf16(ah, bh, acc[n], 0, 0, 0);
            acc[n] = __builtin_amdgcn_mfma_f32_16x16x32_bf16(al, bh, acc[n], 0, 0, 0);
            acc[n] = __builtin_amdgcn_mfma_f32_16x16x32_bf16(ah, bl, acc[n], 0, 0, 0);
        }
    }

    // ---- cross-wave K-reduction via LDS ----
    #pragma unroll
    for (int n = 0; n < 4; ++n)
        #pragma unroll
        for (int r = 0; r < 4; ++r)
            PART[wv * 1024 + lane * 16 + n * 4 + r] = acc[n][r];
    __syncthreads();

    // sum the 4 partials into LG[token][expert]
    // C-layout: token = quad*4 + r, expert = 16n + l16
    //   -> producing lane = (t>>2)*16 + (e&15), reg = (e>>4)*4 + (t&3)
    #pragma unroll
    for (int c = 0; c < 4; ++c) {
        int idx = tid * 4 + c;          // 0..1023
        int t = idx >> 6, e = idx & 63;
        int off = ((t >> 2) * 16 + (e & 15)) * 16 + ((e >> 4) * 4 + (t & 3));
        LG[t * 65 + e] = PART[off] + PART[1024 + off] + PART[2048 + off] + PART[3072 + off];
    }
    __syncthreads();

    // ---- epilogue: each wave handles 4 tokens, lane = expert ----
    for (int i = 0; i < 4; ++i) {
        int tl = wv * 4 + i;
        float v = LG[tl * 65 + lane];

        // argmax, lower-index tie-break (matches jax.lax.top_k)
        float bv = v; int bi = lane;
        #pragma unroll
        for (int off = 1; off < 64; off <<= 1) {
            float ov = __shfl_xor(bv, off, 64);
            int   oi = __shfl_xor(bi, off, 64);
            bool take = (ov > bv) || (ov == bv && oi < bi);
            bv = take ? ov : bv;
            bi = take ? oi : bi;
        }
        float m = bv; int i1 = bi;

        float p = __expf(v - m);
        float s = p;
        #pragma unroll
        for (int off = 1; off < 64; off <<= 1) s += __shfl_xor(s, off, 64);
        float prob = p / s;

        float v2 = (lane == i1) ? -INFINITY : v;
        float bv2 = v2; int bi2 = lane;
        #pragma unroll
        for (int off = 1; off < 64; off <<= 1) {
            float ov = __shfl_xor(bv2, off, 64);
            int   oi = __shfl_xor(bi2, off, 64);
            bool take = (ov > bv2) || (ov == bv2 && oi < bi2);
            bv2 = take ? ov : bv2;
            bi2 = take ? oi : bi2;
        }
        int i2 = bi2;

        float pd = __shfl(prob, i1, 64) + __shfl(prob, i2, 64);
        int t = t0 + tl;
        bool top = (lane == i1) || (lane == i2);

        mask_out[t * 64 + lane]  = top ? 1.f : 0.f;
        rp_out[t * 64 + lane]    = top ? prob / pd : 0.f;
        probs_out[t * 64 + lane] = prob;
        if (lane == 0) {
            idx_out[t * 2]     = (float)i1;
            idx_out[t * 2 + 1] = (float)i2;
        }
    }
}

extern "C" void kernel_launch(void* const* d_in, const int* in_sizes, int n_in,
                              void* d_out, int out_size, void* d_ws, size_t ws_size,
                              hipStream_t stream) {
    const float* x = (const float*)d_in[0];
    const float* W = (const float*)d_in[1];
    float* out = (float*)d_out;

    const int T = in_sizes[0] / D_DIM;      // 16384 tokens
    const int WN = in_sizes[1];             // 131072 elements

    unsigned short* WH = (unsigned short*)d_ws;
    unsigned short* WL = WH + WN;

    float* mask_out  = out;
    float* idx_out   = out + (size_t)T * E_DIM;
    float* rp_out    = idx_out + (size_t)T * 2;
    float* probs_out = rp_out + (size_t)T * E_DIM;

    convert_w<<<dim3(WN / 4 / 256), dim3(256), 0, stream>>>((const float4*)W, WH, WL);
    router_fused<<<dim3(T / TPB), dim3(256), 0, stream>>>(
        x, WH, WL, mask_out, idx_out, rp_out, probs_out);
}

// Round 3
// 208.294 us; speedup vs baseline: 1.2159x; 1.2159x over previous
//
#include <hip/hip_runtime.h>
#include <math.h>

// MoE top-2 router. Round 3: K-split GEMM with global_load_lds staging
// (XOR-swizzled, coalesced, async), x split to bf16 hi/lo at fragment-read
// time, partial logits in ws, then a reduce+softmax+top2 kernel.
//
// x: [16384, 2048] fp32, W: [64, 2048] fp32.
// outputs (concat, fp32): mask [T,64], idx-as-float [T,2],
//                         router_probs [T,64], probs [T,64]

#define D_DIM 2048
#define E_DIM 64

typedef __bf16 bf16x8 __attribute__((ext_vector_type(8)));
typedef unsigned short us8 __attribute__((ext_vector_type(8)));
typedef float f32x4 __attribute__((ext_vector_type(4)));

static __device__ __forceinline__ unsigned short f2bf(float f) {
    unsigned int u = __float_as_uint(f);
    u += 0x7fffu + ((u >> 16) & 1u);   // RNE
    return (unsigned short)(u >> 16);
}
static __device__ __forceinline__ float bf2f(unsigned short h) {
    return __uint_as_float(((unsigned int)h) << 16);
}
static __device__ __forceinline__ void split4(const float4 v, ushort4* h, ushort4* l) {
    h->x = f2bf(v.x); l->x = f2bf(v.x - bf2f(h->x));
    h->y = f2bf(v.y); l->y = f2bf(v.y - bf2f(h->y));
    h->z = f2bf(v.z); l->z = f2bf(v.z - bf2f(h->z));
    h->w = f2bf(v.w); l->w = f2bf(v.w - bf2f(h->w));
}

static __device__ __forceinline__ void gld_lds16(const void* g, void* l) {
    __builtin_amdgcn_global_load_lds(
        (const __attribute__((address_space(1))) unsigned int*)g,
        (__attribute__((address_space(3))) unsigned int*)l,
        16, 0, 0);
}

// ---- pre-convert W (64x2048 fp32) -> bf16 hi/lo, linear layout ----
__global__ __launch_bounds__(256, 1) void convert_w(
    const float4* __restrict__ W4, unsigned short* __restrict__ WH,
    unsigned short* __restrict__ WL)
{
    int i = blockIdx.x * 256 + threadIdx.x;   // float4 index
    float4 v = W4[i];
    ushort4 h, l;
    split4(v, &h, &l);
    *(ushort4*)&WH[i * 4] = h;
    *(ushort4*)&WL[i * 4] = l;
}

// ---- GEMM: block = 64 tokens x K-slice (2048/KS); partials to P ----
template<int KS>
__global__ __launch_bounds__(256, 4) void gemm_part(
    const float* __restrict__ x,
    const unsigned short* __restrict__ WHg, const unsigned short* __restrict__ WLg,
    float* __restrict__ P, int T)
{
    // 16B-slot-swizzled LDS tiles (slot sl holds global slot sl ^ rowkey)
    __shared__ __align__(16) float          XF [64 * 64];  // 16 KB fp32 x tile
    __shared__ __align__(16) unsigned short WHs[64 * 64];  //  8 KB
    __shared__ __align__(16) unsigned short WLs[64 * 64];  //  8 KB

    const int tid  = threadIdx.x;
    const int lane = tid & 63;
    const int wv   = tid >> 6;
    const int quad = lane >> 4;
    const int l16  = lane & 15;

    const int ntb = T >> 6;
    const int tb  = blockIdx.x % ntb;
    const int ksl = blockIdx.x / ntb;
    const int t0  = tb << 6;
    const int NCH = (D_DIM / KS) >> 6;        // 64-k chunks per slice
    const int k0  = ksl * (D_DIM / KS);

    f32x4 acc[4];
    #pragma unroll
    for (int n = 0; n < 4; ++n) { f32x4 z = {0.f, 0.f, 0.f, 0.f}; acc[n] = z; }

    // staging-lane constants
    const int srow = wv * 4 + (lane >> 4);    // + 16*i  -> x row
    const int scg  = lane & 15;               // x float4 col before swizzle
    const int we   = wv * 8 + (lane >> 3);    // + 32*i2 -> W expert row
    const int wo   = lane & 7;                // W k-octet before swizzle

    for (int ch = 0; ch < NCH; ++ch) {
        const int kc = k0 + (ch << 6);        // chunk k base (floats/shorts)

        // ---- async staging, fully coalesced (swizzle via global index) ----
        #pragma unroll
        for (int i = 0; i < 4; ++i) {
            int row = i * 16 + srow;
            int cg  = scg ^ (row & 15);
            gld_lds16(x + (size_t)(t0 + row) * D_DIM + kc + cg * 4,
                      &XF[(i * 256 + wv * 64) * 4]);
        }
        #pragma unroll
        for (int i2 = 0; i2 < 2; ++i2) {
            int e  = i2 * 32 + we;
            int og = wo ^ (e & 7);
            gld_lds16(WHg + (size_t)e * D_DIM + kc + og * 8,
                      &WHs[(i2 * 256 + wv * 64) * 8]);
            gld_lds16(WLg + (size_t)e * D_DIM + kc + og * 8,
                      &WLs[(i2 * 256 + wv * 64) * 8]);
        }
        __syncthreads();

        // ---- compute: 2 k-steps of 32 ----
        #pragma unroll
        for (int ks = 0; ks < 2; ++ks) {
            const int tr = wv * 16 + l16;                 // token row
            const int c0 = ks * 8 + quad * 2;             // float4 col of k-window
            float4 xa = *(const float4*)&XF[(tr * 16 + ( c0      ^ (tr & 15))) * 4];
            float4 xb = *(const float4*)&XF[(tr * 16 + ((c0 + 1) ^ (tr & 15))) * 4];
            ushort4 h0, l0, h1, l1;
            split4(xa, &h0, &l0);
            split4(xb, &h1, &l1);
            union { us8 u; bf16x8 b; } ua, ul;
            ua.u = (us8){h0.x, h0.y, h0.z, h0.w, h1.x, h1.y, h1.z, h1.w};
            ul.u = (us8){l0.x, l0.y, l0.z, l0.w, l1.x, l1.y, l1.z, l1.w};

            #pragma unroll
            for (int n = 0; n < 4; ++n) {
                int e = n * 16 + l16;
                int o = ks * 4 + quad;
                int s = e * 8 + (o ^ (e & 7));
                bf16x8 bh = *(const bf16x8*)&WHs[s * 8];
                bf16x8 bl = *(const bf16x8*)&WLs[s * 8];
                acc[n] = __builtin_amdgcn_mfma_f32_16x16x32_bf16(ua.b, bh, acc[n], 0, 0, 0);
                acc[n] = __builtin_amdgcn_mfma_f32_16x16x32_bf16(ul.b, bh, acc[n], 0, 0, 0);
                acc[n] = __builtin_amdgcn_mfma_f32_16x16x32_bf16(ua.b, bl, acc[n], 0, 0, 0);
            }
        }
        __syncthreads();
    }

    // ---- write partial logits: P[ksl][t][e] ----
    float* Pb = P + ((size_t)ksl * T + t0) * 64;
    #pragma unroll
    for (int n = 0; n < 4; ++n)
        #pragma unroll
        for (int r = 0; r < 4; ++r)
            Pb[(wv * 16 + quad * 4 + r) * 64 + n * 16 + l16] = acc[n][r];
}

// ---- reduce partials + softmax + top-2 + outputs; wave per 4 tokens ----
template<int KS>
__global__ __launch_bounds__(256, 4) void reduce_router(
    const float* __restrict__ P, int T,
    float* __restrict__ mask_out, float* __restrict__ idx_out,
    float* __restrict__ rp_out, float* __restrict__ probs_out)
{
    const int tid  = threadIdx.x;
    const int lane = tid & 63;
    const int wv   = tid >> 6;

    for (int i = 0; i < 4; ++i) {
        int t = blockIdx.x * 16 + wv * 4 + i;
        float v = 0.f;
        #pragma unroll
        for (int s = 0; s < KS; ++s)
            v += P[((size_t)s * T + t) * 64 + lane];

        // argmax, lower-index tie-break (matches jax.lax.top_k)
        float bv = v; int bi = lane;
        #pragma unroll
        for (int off = 1; off < 64; off <<= 1) {
            float ov = __shfl_xor(bv, off, 64);
            int   oi = __shfl_xor(bi, off, 64);
            bool take = (ov > bv) || (ov == bv && oi < bi);
            bv = take ? ov : bv;
            bi = take ? oi : bi;
        }
        float m = bv; int i1 = bi;

        float p = __expf(v - m);
        float s = p;
        #pragma unroll
        for (int off = 1; off < 64; off <<= 1) s += __shfl_xor(s, off, 64);
        float prob = p / s;

        float v2 = (lane == i1) ? -INFINITY : v;
        float bv2 = v2; int bi2 = lane;
        #pragma unroll
        for (int off = 1; off < 64; off <<= 1) {
            float ov = __shfl_xor(bv2, off, 64);
            int   oi = __shfl_xor(bi2, off, 64);
            bool take = (ov > bv2) || (ov == bv2 && oi < bi2);
            bv2 = take ? ov : bv2;
            bi2 = take ? oi : bi2;
        }
        int i2 = bi2;

        float pd = __shfl(prob, i1, 64) + __shfl(prob, i2, 64);
        bool top = (lane == i1) || (lane == i2);

        mask_out[(size_t)t * 64 + lane]  = top ? 1.f : 0.f;
        rp_out[(size_t)t * 64 + lane]    = top ? prob / pd : 0.f;
        probs_out[(size_t)t * 64 + lane] = prob;
        if (lane == 0) {
            idx_out[(size_t)t * 2]     = (float)i1;
            idx_out[(size_t)t * 2 + 1] = (float)i2;
        }
    }
}

extern "C" void kernel_launch(void* const* d_in, const int* in_sizes, int n_in,
                              void* d_out, int out_size, void* d_ws, size_t ws_size,
                              hipStream_t stream) {
    const float* x = (const float*)d_in[0];
    const float* W = (const float*)d_in[1];
    float* out = (float*)d_out;

    const int T  = in_sizes[0] / D_DIM;     // 16384 tokens
    const int WN = in_sizes[1];             // 131072 elements

    unsigned short* WH = (unsigned short*)d_ws;
    unsigned short* WL = WH + WN;
    float* P = (float*)(WL + WN);           // partials after 512 KB of W

    float* mask_out  = out;
    float* idx_out   = out + (size_t)T * E_DIM;
    float* rp_out    = idx_out + (size_t)T * 2;
    float* probs_out = rp_out + (size_t)T * E_DIM;

    const size_t avail = ws_size - (size_t)WN * 4;
    const size_t slice_bytes = (size_t)T * 64 * 4;

    convert_w<<<dim3(WN / 1024), dim3(256), 0, stream>>>((const float4*)W, WH, WL);

    if (avail >= 4 * slice_bytes) {
        gemm_part<4><<<dim3((T / 64) * 4), dim3(256), 0, stream>>>(x, WH, WL, P, T);
        reduce_router<4><<<dim3(T / 16), dim3(256), 0, stream>>>(
            P, T, mask_out, idx_out, rp_out, probs_out);
    } else if (avail >= 2 * slice_bytes) {
        gemm_part<2><<<dim3((T / 64) * 2), dim3(256), 0, stream>>>(x, WH, WL, P, T);
        reduce_router<2><<<dim3(T / 16), dim3(256), 0, stream>>>(
            P, T, mask_out, idx_out, rp_out, probs_out);
    } else {
        gemm_part<1><<<dim3(T / 64), dim3(256), 0, stream>>>(x, WH, WL, P, T);
        reduce_router<1><<<dim3(T / 16), dim3(256), 0, stream>>>(
            P, T, mask_out, idx_out, rp_out, probs_out);
    }
}